// Round 3
// baseline (740.286 us; speedup 1.0000x reference)
//
#include <hip/hip_runtime.h>

// ---------------------------------------------------------------------------
// TraceSemanticHandshakeV342  (b=4, m=256, h=64, d=256, CAT=1283)
// R3: barrier-free / LDS-free all-register design.
//   - grid 2048 x 64 threads: one WAVE owns 32 rows (l15 = row-within-16-tile).
//   - GEMM1 computed transposed: C1T = W1g^T * X^T.
//       A-operand = W1 (gamma-folded bf16) in FRAGMENT-ORDER in d_ws:
//         each frag load = 1KB fully coalesced (lane*16B contiguous).
//       B-operand = X rows straight from global f32 (8 consec floats/lane),
//         packed to bf16 in-reg; row stats accumulated from same values.
//   - C/D layout: col=l15=ROW -> LN stats are per-lane, zero exchange.
//   - y1 -> GEMM2 A-operand via ds_bpermute (no LDS alloc, no barrier).
//   - GEMM2: C2 = y1 * W2 with W2 in fragment-order bf16; coalesced stores.
// ---------------------------------------------------------------------------

typedef float  f32x4 __attribute__((ext_vector_type(4)));
typedef short  s16x8 __attribute__((ext_vector_type(8)));

__device__ __forceinline__ unsigned short f2bf(float f) {
    return (unsigned short)((__builtin_bit_cast(unsigned, f) + 0x8000u) >> 16);
}
__device__ __forceinline__ unsigned pack_bf2(float lo, float hi) {
    unsigned a = __builtin_bit_cast(unsigned, hi) + 0x8000u;
    unsigned b = __builtin_bit_cast(unsigned, lo) + 0x8000u;
    return __builtin_amdgcn_perm(a, b, 0x07060302u);  // {hi[31:16], lo[31:16]}
}
__device__ __forceinline__ float gelu_t(float x) {
    float u2 = 1.5957691216057308f * x + 0.07135481627f * (x * x * x);
    float e  = __expf(u2);
    float r  = __builtin_amdgcn_rcpf(e + 1.0f);
    return x - x * r;
}
__device__ __forceinline__ float bperm(int idx, float v) {
    return __builtin_bit_cast(float,
        __builtin_amdgcn_ds_bpermute(idx, __builtin_bit_cast(int, v)));
}

// ---------------------------------------------------------------------------
// Prep: fragment-order weights + LN column sums.
//  w1f shorts[327680]: idx -> j=idx&7, lane=(idx>>3)&63, mt=(idx>>9)&15,
//    fid=idx>>13 (0..39): value = bf16(gamma[k]*W1[k*256+n1]),
//    k = fid*32 + (lane>>4)*8 + j,  n1 = mt*16 + (lane&15).
//  w2f shorts[65536]: j,lane,nt=(..)&15,kc=idx>>13 (0..7):
//    value = bf16(W2[k*256+n2]), k = kc*32+(lane>>4)*8+j, n2 = nt*16+(lane&15).
//  Sg[n] = sum_k gamma_k W1[k,n];  SbB[n] = sum_k beta_k W1[k,n] + b1[n].
// ---------------------------------------------------------------------------
__global__ void __launch_bounds__(256)
prep_k(const float* __restrict__ W1, const float* __restrict__ W2,
       const float* __restrict__ gamma, const float* __restrict__ beta,
       const float* __restrict__ b1,
       float* __restrict__ Sg, float* __restrict__ SbB,
       short* __restrict__ w1f, short* __restrict__ w2f)
{
    const int blk = blockIdx.x;
    if (blk < 1280) {
        int idx = blk * 256 + threadIdx.x;
        int j = idx & 7, lane = (idx >> 3) & 63;
        int mt = (idx >> 9) & 15, fid = idx >> 13;
        int k  = fid * 32 + ((lane >> 4) << 3) + j;
        int n1 = mt * 16 + (lane & 15);
        w1f[idx] = (short)f2bf(gamma[k] * W1[k * 256 + n1]);
    } else if (blk < 1536) {
        int idx = (blk - 1280) * 256 + threadIdx.x;
        int j = idx & 7, lane = (idx >> 3) & 63;
        int nt = (idx >> 9) & 15, kc = idx >> 13;
        int k  = kc * 32 + ((lane >> 4) << 3) + j;
        int n2 = nt * 16 + (lane & 15);
        w2f[idx] = (short)f2bf(W2[k * 256 + n2]);
    } else {
        int kb = (blk - 1536) * 32;
        int n  = threadIdx.x;
        float sg = 0.f, sb = 0.f;
#pragma unroll
        for (int j = 0; j < 32; ++j) {
            int k = kb + j;
            float w = W1[k * 256 + n];
            sg += gamma[k] * w;
            sb += beta[k]  * w;
        }
        if (blk == 1536) sb += b1[n];
        atomicAdd(&Sg[n], sg);
        atomicAdd(&SbB[n], sb);
    }
}

// ---------------------------------------------------------------------------
// Main: 2048 blocks x 64 threads (1 wave), 32 rows/wave.  No LDS, no barriers.
// ---------------------------------------------------------------------------
__global__ void __launch_bounds__(64, 2)
fused_main(const float* __restrict__ token, const float* __restrict__ step,
           const float* __restrict__ dyn,   const float* __restrict__ sem,
           const float* __restrict__ trace, const float* __restrict__ rel,
           const float* __restrict__ vis,   const float* __restrict__ gamma,
           const float* __restrict__ beta,  const float* __restrict__ W1,
           const float* __restrict__ b2v,
           const float* __restrict__ Sg,    const float* __restrict__ SbB,
           const short* __restrict__ w1f,   const short* __restrict__ w2f,
           float* __restrict__ out)
{
    const int lane  = threadIdx.x;
    const int blk   = blockIdx.x;
    const int bm    = blk >> 1;
    const int hrow0 = (blk & 1) * 32;
    const int b_i   = bm >> 8;
    const int l15   = lane & 15;
    const int q     = lane >> 4;

    // X row base pointers per (seg, rt)
    const float* xb[5][2];
    xb[0][0] = xb[0][1] = token + bm * 256;
#pragma unroll
    for (int rt = 0; rt < 2; ++rt) {
        int hr = hrow0 + rt * 16 + l15;
        int gr = blk * 32 + rt * 16 + l15;
        xb[1][rt] = step  + (b_i * 64 + hr) * 256;
        xb[2][rt] = dyn   + gr * 256;
        xb[3][rt] = sem   + gr * 256;
        xb[4][rt] = trace + gr * 256;
    }

    // epilogue-1 per-lane constant vectors (value for n1 = i*64 + lane)
    float cS[4], cB[4], c0[4], c1[4], c2[4];
#pragma unroll
    for (int i = 0; i < 4; ++i) {
        cS[i] = Sg[i * 64 + lane];
        cB[i] = SbB[i * 64 + lane];
        c0[i] = W1[1280 * 256 + i * 64 + lane];
        c1[i] = W1[1281 * 256 + i * 64 + lane];
        c2[i] = W1[1282 * 256 + i * 64 + lane];
    }

    float s1[2] = {0.f, 0.f}, s2[2] = {0.f, 0.f};
    float rs_r[2], mr_r[2], t0r[2], t1r[2], t2r[2];
    s16x8 a2f[2][8];                       // GEMM2 A-fragments (y1, bf16)

    const int bidx = (lane & 16) * 8 + l15 * 4;   // a2f bperm base index

#pragma unroll
    for (int H = 0; H < 2; ++H) {
        f32x4 acc[2][8];
#pragma unroll
        for (int rt = 0; rt < 2; ++rt)
#pragma unroll
            for (int mt8 = 0; mt8 < 8; ++mt8)
                acc[rt][mt8] = (f32x4){0.f, 0.f, 0.f, 0.f};

#pragma unroll
        for (int seg = 0; seg < 5; ++seg) {
#pragma unroll
            for (int kc = 0; kc < 8; ++kc) {
                s16x8 bx[2];
#pragma unroll
                for (int rt = 0; rt < 2; ++rt) {
                    const float4* p = (const float4*)xb[seg][rt];
                    float4 f0 = p[kc * 8 + q * 2];
                    float4 f1 = p[kc * 8 + q * 2 + 1];
                    if (H == 0) {
                        s1[rt] += (f0.x + f0.y) + (f0.z + f0.w)
                                + (f1.x + f1.y) + (f1.z + f1.w);
                        s2[rt] += f0.x * f0.x + f0.y * f0.y + f0.z * f0.z
                                + f0.w * f0.w + f1.x * f1.x + f1.y * f1.y
                                + f1.z * f1.z + f1.w * f1.w;
                    }
                    uint4 pk;
                    pk.x = pack_bf2(f0.x, f0.y);
                    pk.y = pack_bf2(f0.z, f0.w);
                    pk.z = pack_bf2(f1.x, f1.y);
                    pk.w = pack_bf2(f1.z, f1.w);
                    bx[rt] = __builtin_bit_cast(s16x8, pk);
                }
#pragma unroll
                for (int mt8 = 0; mt8 < 8; ++mt8) {
                    const s16x8 a = *(const s16x8*)(w1f
                        + (((seg * 8 + kc) * 16 + H * 8 + mt8) << 9)
                        + (lane << 3));
                    acc[0][mt8] = __builtin_amdgcn_mfma_f32_16x16x32_bf16(
                        a, bx[0], acc[0][mt8], 0, 0, 0);
                    acc[1][mt8] = __builtin_amdgcn_mfma_f32_16x16x32_bf16(
                        a, bx[1], acc[1][mt8], 0, 0, 0);
                }
            }
        }

        if (H == 0) {
            // finalize LN stats; every lane ends with its row's (rt*16+l15) stats
#pragma unroll
            for (int rt = 0; rt < 2; ++rt) {
                float a = s1[rt], b = s2[rt];
                a += __shfl_xor(a, 16); a += __shfl_xor(a, 32);
                b += __shfl_xor(b, 16); b += __shfl_xor(b, 32);
                int g = blk * 32 + rt * 16 + l15;
                float x0 = rel[g * 2 + 0], x1 = rel[g * 2 + 1], x2 = vis[g];
                float S1 = a + x0 + x1 + x2;
                float S2 = b + x0 * x0 + x1 * x1 + x2 * x2;
                const float inv = 1.0f / 1283.0f;
                float mu  = S1 * inv;
                float var = S2 * inv - mu * mu;
                float rs  = rsqrtf(var + 1e-5f);
                rs_r[rt] = rs;
                mr_r[rt] = mu * rs;
                t0r[rt] = (x0 - mu) * rs * gamma[1280] + beta[1280];
                t1r[rt] = (x1 - mu) * rs * gamma[1281] + beta[1281];
                t2r[rt] = (x2 - mu) * rs * gamma[1282] + beta[1282];
            }
        }

        // ---- epilogue-1 (this n1-half): LN fixup + tail + GELU -> y --------
        float y[2][8][4];
#pragma unroll
        for (int mt8 = 0; mt8 < 8; ++mt8) {
            const int mtg  = H * 8 + mt8;
            const int ci   = mtg >> 2;           // compile-time reg index
            const int coff = (mtg & 3) * 64;
#pragma unroll
            for (int r4 = 0; r4 < 4; ++r4) {
                int idx = ((lane & 48) + coff + r4 * 4);
                float sg  = bperm(idx, cS[ci]);
                float sbb = bperm(idx, cB[ci]);
                float w0  = bperm(idx, c0[ci]);
                float w1v = bperm(idx, c1[ci]);
                float w2v = bperm(idx, c2[ci]);
#pragma unroll
                for (int rt = 0; rt < 2; ++rt) {
                    float base = fmaf(t0r[rt], w0, sbb);
                    base = fmaf(t1r[rt], w1v, base);
                    base = fmaf(t2r[rt], w2v, base);
                    float v = fmaf(rs_r[rt], acc[rt][mt8][r4],
                                   fmaf(-mr_r[rt], sg, base));
                    y[rt][mt8][r4] = gelu_t(v);
                }
            }
        }

        // ---- build GEMM2 A-fragments for kc2 in {4H..4H+3} via bpermute ----
#pragma unroll
        for (int kc2l = 0; kc2l < 4; ++kc2l) {
#pragma unroll
            for (int rt = 0; rt < 2; ++rt) {
                float v[8];
#pragma unroll
                for (int j = 0; j < 8; ++j) {
                    int idxj = bidx + (j >> 2) * 64;
                    float va = bperm(idxj, y[rt][kc2l * 2 + 0][j & 3]);
                    float vb = bperm(idxj, y[rt][kc2l * 2 + 1][j & 3]);
                    v[j] = (lane & 32) ? vb : va;
                }
                uint4 pk;
                pk.x = pack_bf2(v[0], v[1]);
                pk.y = pack_bf2(v[2], v[3]);
                pk.z = pack_bf2(v[4], v[5]);
                pk.w = pack_bf2(v[6], v[7]);
                a2f[rt][H * 4 + kc2l] = __builtin_bit_cast(s16x8, pk);
            }
        }
    }

    // ---- GEMM2: C2 = y1 * W2  (A = a2f in regs, B = w2f frag-order) --------
#pragma unroll
    for (int nthalf = 0; nthalf < 2; ++nthalf) {
        f32x4 acc2[2][8];
#pragma unroll
        for (int rt = 0; rt < 2; ++rt)
#pragma unroll
            for (int nt8 = 0; nt8 < 8; ++nt8)
                acc2[rt][nt8] = (f32x4){0.f, 0.f, 0.f, 0.f};

#pragma unroll
        for (int kc2 = 0; kc2 < 8; ++kc2) {
#pragma unroll
            for (int nt8 = 0; nt8 < 8; ++nt8) {
                const s16x8 b2 = *(const s16x8*)(w2f
                    + ((kc2 * 16 + nthalf * 8 + nt8) << 9) + (lane << 3));
                acc2[0][nt8] = __builtin_amdgcn_mfma_f32_16x16x32_bf16(
                    a2f[0][kc2], b2, acc2[0][nt8], 0, 0, 0);
                acc2[1][nt8] = __builtin_amdgcn_mfma_f32_16x16x32_bf16(
                    a2f[1][kc2], b2, acc2[1][nt8], 0, 0, 0);
            }
        }
        // epilogue-2: + b2, GELU, coalesced store (16 dwords x 4 rows / instr)
#pragma unroll
        for (int nt8 = 0; nt8 < 8; ++nt8) {
            int n2 = (nthalf * 8 + nt8) * 16 + l15;
            float bb = b2v[n2];
#pragma unroll
            for (int rt = 0; rt < 2; ++rt)
#pragma unroll
                for (int r4 = 0; r4 < 4; ++r4) {
                    int row = blk * 32 + rt * 16 + q * 4 + r4;
                    out[row * 256 + n2] = gelu_t(acc2[rt][nt8][r4] + bb);
                }
        }
    }
}

// ---------------------------------------------------------------------------
extern "C" void kernel_launch(void* const* d_in, const int* in_sizes, int n_in,
                              void* d_out, int out_size, void* d_ws, size_t ws_size,
                              hipStream_t stream) {
    const float* token = (const float*)d_in[0];
    const float* step  = (const float*)d_in[1];
    const float* dyn   = (const float*)d_in[2];
    const float* sem   = (const float*)d_in[3];
    const float* trace = (const float*)d_in[4];
    const float* rel   = (const float*)d_in[5];
    const float* vis   = (const float*)d_in[6];
    const float* gamma = (const float*)d_in[7];
    const float* beta  = (const float*)d_in[8];
    const float* W1    = (const float*)d_in[9];
    const float* b1    = (const float*)d_in[10];
    const float* W2    = (const float*)d_in[11];
    const float* b2    = (const float*)d_in[12];

    // ws: Sg[256] f32 @0, SbB[256] f32 @1KB, w1f bf16 @2048 (655360B),
    //     w2f bf16 @657408 (131072B).  Total 788480 B.
    float* Sg  = (float*)d_ws;
    float* SbB = Sg + 256;
    short* w1f = (short*)((char*)d_ws + 2048);
    short* w2f = w1f + 1280 * 256;
    float* out = (float*)d_out;

    hipMemsetAsync(d_ws, 0, 2048, stream);
    hipLaunchKernelGGL(prep_k, dim3(1576), dim3(256), 0, stream,
                       W1, W2, gamma, beta, b1, Sg, SbB, w1f, w2f);
    hipLaunchKernelGGL(fused_main, dim3(2048), dim3(64), 0, stream,
                       token, step, dyn, sem, trace, rel, vis, gamma, beta,
                       W1, b2, Sg, SbB, w1f, w2f, out);
}